// Round 4
// baseline (1480.409 us; speedup 1.0000x reference)
//
#include <hip/hip_runtime.h>

// LSTM_1030792151143: 2-layer LSTM (B=2048, T=1000, F=40, H1=8, H2=6) + tanh + FC + sigmoid.
//
// Round 4 (bisect): round-2's PROVEN lstm_rec (absmax 0.0) with exactly one change —
// the xg prefetch loads directly into the dead rotation slot buf[n&7] (consumed 7
// iterations later) instead of round-2's same-iteration register copy which forced a
// vmcnt drain every step. Plus the vectorized xg_pass (float4 VMEM loads instead of
// the scalar-cache s_load path that plateaued at 1.16 TB/s).

constexpr int Bn = 2048, Tn = 1000, Fn = 40;
constexpr int H1n = 8, H2n = 6;
constexpr int G1n = 32, G2n = 24;
constexpr int PF = 8;   // xg prefetch depth (steps)

__device__ __forceinline__ float frcp(float x) { return __builtin_amdgcn_rcpf(x); }
__device__ __forceinline__ float act_abc(float A, float Bc, float C, float x) {
    return fmaf(A, frcp(1.0f + __expf(Bc * x)), C);   // sigmoid: (1,-1,0); tanh: (2,-2,-1)
}
__device__ __forceinline__ float ftanh(float x) {
    return fmaf(2.0f, frcp(1.0f + __expf(-2.0f * x)), -1.0f);
}
__device__ __forceinline__ float bcast(float v, int k) {   // lane-k broadcast via readlane
    return __uint_as_float(__builtin_amdgcn_readlane(__float_as_uint(v), k));
}

// ---------------- Pass 1: input projection (vector loads) ----------------
__global__ __launch_bounds__(256, 3) void xg_pass(
    const float* __restrict__ x, const float* __restrict__ W_ih1,
    const float* __restrict__ b_ih1, const float* __restrict__ b_hh1,
    float* __restrict__ xg)
{
    const int lane = threadIdx.x & 63;
    const int w    = threadIdx.x >> 6;       // 4 waves/block
    const int b    = blockIdx.x;             // one batch per block
    const int s    = lane >> 5;              // step parity within pair
    const int g    = lane & 31;              // gate owned
    const int t0   = w * (Tn / 4) + s;       // wave covers 250 steps, this half 125

    float wv[Fn];
#pragma unroll
    for (int k = 0; k < Fn; ++k) wv[k] = W_ih1[g * Fn + k];
    const float bias = b_ih1[g] + b_hh1[g];

    const float* __restrict__ xb = x  + (size_t)b * Tn * Fn;
    float* __restrict__       og = xg + (size_t)b * Tn * G1n;

#pragma unroll 2
    for (int i = 0; i < Tn / 8; ++i) {       // 125 iterations
        const int t = t0 + 2 * i;
        const float4* __restrict__ p = (const float4*)(xb + (size_t)t * Fn);
        float4 r[10];
#pragma unroll
        for (int k = 0; k < 10; ++k) r[k] = p[k];
        float a0 = bias, a1 = 0.f, a2 = 0.f, a3 = 0.f;
#pragma unroll
        for (int k = 0; k < 10; ++k) {
            a0 = fmaf(r[k].x, wv[4 * k + 0], a0);
            a1 = fmaf(r[k].y, wv[4 * k + 1], a1);
            a2 = fmaf(r[k].z, wv[4 * k + 2], a2);
            a3 = fmaf(r[k].w, wv[4 * k + 3], a3);
        }
        og[(size_t)t * G1n + g] = (a0 + a1) + (a2 + a3);
    }
}

// ---------------- Pass 2: recurrence (round-2 proven kernel + real prefetch) ----------------
__global__ __launch_bounds__(256, 2) void lstm_rec(
    const float* __restrict__ xg,
    const float* __restrict__ W_hh1,
    const float* __restrict__ W_ih2, const float* __restrict__ W_hh2,
    const float* __restrict__ b_ih2, const float* __restrict__ b_hh2,
    const float* __restrict__ W_fc,  const float* __restrict__ b_fc,
    float* __restrict__ out)
{
    const int lane  = threadIdx.x & 63;
    const int wslot = __builtin_amdgcn_readfirstlane((int)(threadIdx.x >> 6));
    const int b     = blockIdx.x * 4 + wslot;     // 512 blocks * 4 waves

    const int g  = lane & 31;                     // L1 gate owned
    const int g2 = (g < G2n) ? g : (G2n - 1);     // L2 gate (clamped dup)
    const int j1 = lane & 7;
    const int j2 = g % H2n;

    float whh1[H1n];
#pragma unroll
    for (int k = 0; k < H1n; ++k) whh1[k] = W_hh1[g * H1n + k];
    float wih2[H1n];
#pragma unroll
    for (int k = 0; k < H1n; ++k) wih2[k] = W_ih2[g2 * H1n + k];
    float whh2[H2n];
#pragma unroll
    for (int k = 0; k < H2n; ++k) whh2[k] = W_hh2[g2 * H2n + k];
    const float bias2 = b_ih2[g2] + b_hh2[g2];

    const bool t1 = (g >= 16 && g < 24);          // L1 cell gate -> tanh
    const float A1 = t1 ? 2.f : 1.f, Bc1 = t1 ? -2.f : -1.f, C1 = t1 ? -1.f : 0.f;
    const bool t2 = (g2 >= 12 && g2 < 18);        // L2 cell gate -> tanh
    const float A2 = t2 ? 2.f : 1.f, Bc2 = t2 ? -2.f : -1.f, C2 = t2 ? -1.f : 0.f;

    float c1 = 0.f, c2 = 0.f;
    float h1s[H1n], th1s[H1n], h2s[H2n];
#pragma unroll
    for (int k = 0; k < H1n; ++k) { h1s[k] = 0.f; th1s[k] = 0.f; }
#pragma unroll
    for (int k = 0; k < H2n; ++k) h2s[k] = 0.f;

    const float* __restrict__ xgb = xg + (size_t)b * Tn * G1n + g;

    float buf[PF];
#pragma unroll
    for (int i = 0; i < PF; ++i) buf[i] = xgb[(size_t)i * G1n];

    float a_pre = buf[0];                          // t=0: h1=0 so preact = xg

#pragma unroll 8
    for (int t = 0; t < Tn; ++t) {
        const int r = t & (PF - 1);                // constant after unroll-8

        // REAL prefetch: load xg[t+PF] DIRECTLY into the dead slot (its old value
        // was consumed last iteration). Read 7 iterations later -> compiler can
        // hold vmcnt(7) instead of draining every step.
        {
            int tp = t + PF; if (tp > Tn - 1) tp = Tn - 1;
            buf[r] = xgb[(size_t)tp * G1n];
        }

        // ---- layer 1 gate + state ----
        const float gv  = act_abc(A1, Bc1, C1, a_pre);
        const float iv  = __shfl(gv, j1);
        const float fv  = __shfl(gv, j1 + 8);
        const float gcv = __shfl(gv, j1 + 16);
        const float ov  = __shfl(gv, j1 + 24);
        c1 = fmaf(fv, c1, iv * gcv);
        const float h1v  = ov * ftanh(c1);
        const float th1v = ftanh(h1v);

#pragma unroll
        for (int k = 0; k < H1n; ++k) h1s[k]  = bcast(h1v, k);
#pragma unroll
        for (int k = 0; k < H1n; ++k) th1s[k] = bcast(th1v, k);

        // ---- next-step L1 preactivation (pipelined) ----
        {
            float a0 = buf[(r + 1) & (PF - 1)], a1 = 0.f;
#pragma unroll
            for (int k = 0; k < H1n; k += 2) {
                a0 = fmaf(h1s[k],     whh1[k],     a0);
                a1 = fmaf(h1s[k + 1], whh1[k + 1], a1);
            }
            a_pre = a0 + a1;
        }

        // ---- layer 2 full step (same t) ----
        float a20 = bias2, a21 = 0.f;
#pragma unroll
        for (int k = 0; k < H1n; k += 2) {
            a20 = fmaf(th1s[k],     wih2[k],     a20);
            a21 = fmaf(th1s[k + 1], wih2[k + 1], a21);
        }
#pragma unroll
        for (int k = 0; k < H2n; k += 2) {
            a20 = fmaf(h2s[k],     whh2[k],     a20);
            a21 = fmaf(h2s[k + 1], whh2[k + 1], a21);
        }
        const float gv2  = act_abc(A2, Bc2, C2, a20 + a21);
        const float iv2  = __shfl(gv2, j2);
        const float fv2  = __shfl(gv2, j2 + 6);
        const float gcv2 = __shfl(gv2, j2 + 12);
        const float ov2  = __shfl(gv2, j2 + 18);
        c2 = fmaf(fv2, c2, iv2 * gcv2);
        const float h2v = ov2 * ftanh(c2);

#pragma unroll
        for (int k = 0; k < H2n; ++k) h2s[k] = bcast(h2v, k);
    }

    if (lane == 0) {
        float a = b_fc[0];
#pragma unroll
        for (int k = 0; k < H2n; ++k) a = fmaf(ftanh(h2s[k]), W_fc[k], a);
        out[b] = frcp(1.0f + __expf(-a));
    }
}

extern "C" void kernel_launch(void* const* d_in, const int* in_sizes, int n_in,
                              void* d_out, int out_size, void* d_ws, size_t ws_size,
                              hipStream_t stream) {
    (void)in_sizes; (void)n_in; (void)out_size; (void)ws_size;
    const float* x     = (const float*)d_in[0];
    const float* W_ih1 = (const float*)d_in[1];
    const float* W_hh1 = (const float*)d_in[2];
    const float* b_ih1 = (const float*)d_in[3];
    const float* b_hh1 = (const float*)d_in[4];
    const float* W_ih2 = (const float*)d_in[5];
    const float* W_hh2 = (const float*)d_in[6];
    const float* b_ih2 = (const float*)d_in[7];
    const float* b_hh2 = (const float*)d_in[8];
    const float* W_fc  = (const float*)d_in[9];
    const float* b_fc  = (const float*)d_in[10];
    float* out = (float*)d_out;
    float* xgw = (float*)d_ws;                      // 2048*1000*32*4 = 262 MB

    xg_pass<<<dim3(Bn), dim3(256), 0, stream>>>(x, W_ih1, b_ih1, b_hh1, xgw);
    lstm_rec<<<dim3(Bn / 4), dim3(256), 0, stream>>>(xgw, W_hh1, W_ih2, W_hh2,
                                                     b_ih2, b_hh2, W_fc, b_fc, out);
}